// Round 13
// baseline (277.282 us; speedup 1.0000x reference)
//
#include <hip/hip_runtime.h>

#define NPATCH 4096
#define NFRAG 49152          // 96 ktiles * 8 ntiles * 64 lanes  (w1 frags per half)
#define NA    1572864        // 96 ktiles * 256 mtiles * 64 lanes (x frags per half)

typedef __attribute__((ext_vector_type(8))) __bf16 bf16x8;
typedef __attribute__((ext_vector_type(4))) __bf16 bf16x4;
typedef __attribute__((ext_vector_type(4))) float f32x4;

// ---------------- prep: pack pw2 weights bf16 in MFMA fragment order ----------------
__global__ __launch_bounds__(256) void prep_kernel(const float* __restrict__ pw2_w,
                                                   bf16x8* __restrict__ wpk) {
  int tid = blockIdx.x * 256 + threadIdx.x;
  int l = tid & 63, nt = (tid >> 6) & 7, kt = (tid >> 9) & 3, e = tid >> 11;
  int n = nt * 16 + (l & 15);
  int k = kt * 32 + (l >> 4) * 8;
  const float* src = &pw2_w[((size_t)(e * 128 + n)) * 128 + k];
  float4 a = *(const float4*)src;
  float4 b = *(const float4*)(src + 4);
  bf16x8 r = { (__bf16)a.x, (__bf16)a.y, (__bf16)a.z, (__bf16)a.w,
               (__bf16)b.x, (__bf16)b.y, (__bf16)b.z, (__bf16)b.w };
  wpk[tid] = r;
}

// ---------------- prep: split gate w1 into hi/lo bf16 MFMA B-fragments ----------------
__global__ __launch_bounds__(256) void prep_w1(const float* __restrict__ w1,
                                               bf16x8* __restrict__ w1f) {
  int tid = blockIdx.x * 256 + threadIdx.x;    // 192 blocks -> 49152 threads
  int l = tid & 63, nt = (tid >> 6) & 7, ktg = tid >> 9;
  int k0 = ktg * 32 + (l >> 4) * 8, d = nt * 16 + (l & 15);
  bf16x8 h, lo;
#pragma unroll
  for (int j = 0; j < 8; ++j) {
    float v = w1[(size_t)(k0 + j) * 128 + d];
    __bf16 hv = (__bf16)v;
    h[j] = hv;
    lo[j] = (__bf16)(v - (float)hv);
  }
  w1f[tid] = h;
  w1f[NFRAG + tid] = lo;
}

// ---------------- prep: split x into hi/lo bf16 MFMA A-fragments ----------------
// afr[(ktg*256+mt)*64+l] = hi ; afr[NA + same] = lo
// lane l of m-tile mt holds row mt*16+(l&15), k = ktg*32+(l>>4)*8 .. +8
__global__ __launch_bounds__(256) void prep_x(const float* __restrict__ x,
                                              bf16x8* __restrict__ afr) {
  int tid = blockIdx.x * 256 + threadIdx.x;    // 6144 blocks
  int l   = tid & 63;
  int mt  = (tid >> 6) & 255;
  int ktg = tid >> 14;
  int gp = mt * 16 + (l & 15);
  int b = gp >> 8, ph = (gp >> 4) & 15, pwc = gp & 15;
  int k0 = ktg * 32 + (l >> 4) * 8;
  int c = k0 >> 10, r = (k0 >> 5) & 31, j = k0 & 31;
  const float* src = &x[((size_t)(b * 3 + c) * 512 + ph * 32 + r) * 512 + pwc * 32 + j];
  float4 v0 = *(const float4*)src;
  float4 v1 = *(const float4*)(src + 4);
  float av[8] = {v0.x, v0.y, v0.z, v0.w, v1.x, v1.y, v1.z, v1.w};
  bf16x8 h, lo;
#pragma unroll
  for (int q = 0; q < 8; ++q) {
    __bf16 hv = (__bf16)av[q];
    h[q] = hv;
    lo[q] = (__bf16)(av[q] - (float)hv);
  }
  afr[tid] = h;            // tid == (ktg*256+mt)*64 + l
  afr[NA + tid] = lo;
}

// ---------------- gate: one wave per 16x16 output tile, no LDS, no barriers ----------------
// 2048 blocks x 64 thr; mt = bid&255 (so a patch-tile's 8 n-blocks share an XCD).
// MFMA sequence (kt order, acc rotation, final reduction) bit-identical to the
// r10 gate -> logits unchanged to the bit.
__global__ __launch_bounds__(64) void gate_wave(
    const bf16x8* __restrict__ afr, const bf16x8* __restrict__ w1f,
    float* __restrict__ hfull)
{
  const int l  = threadIdx.x;
  const int mt = blockIdx.x & 255;
  const int nt = blockIdx.x >> 8;
  const bf16x8* Ap = afr + (size_t)mt * 64 + l;
  const bf16x8* Bp = w1f + (size_t)nt * 64 + l;

  f32x4 accA[4], accB[4];
#pragma unroll
  for (int i = 0; i < 4; ++i) {
    accA[i] = (f32x4){0.f, 0.f, 0.f, 0.f};
    accB[i] = (f32x4){0.f, 0.f, 0.f, 0.f};
  }

#pragma unroll 4
  for (int kt = 0; kt < 96; ++kt) {
    bf16x8 ah = Ap[(size_t)kt * 16384];
    bf16x8 al = Ap[(size_t)kt * 16384 + NA];
    bf16x8 bh = Bp[(size_t)kt * 512];
    bf16x8 bl = Bp[(size_t)kt * 512 + NFRAG];
    const int r_ = kt & 3;
    accA[r_] = __builtin_amdgcn_mfma_f32_16x16x32_bf16(ah, bh, accA[r_], 0, 0, 0);
    accB[r_] = __builtin_amdgcn_mfma_f32_16x16x32_bf16(ah, bl, accB[r_], 0, 0, 0);
    accB[r_] = __builtin_amdgcn_mfma_f32_16x16x32_bf16(al, bh, accB[r_], 0, 0, 0);
  }

  f32x4 sA = (accA[0] + accA[1]) + (accA[2] + accA[3]);
  f32x4 sB = (accB[0] + accB[1]) + (accB[2] + accB[3]);
  const int d  = nt * 16 + (l & 15);
  const int m0 = mt * 16 + (l >> 4) * 4;
#pragma unroll
  for (int r = 0; r < 4; ++r)
    hfull[(size_t)(m0 + r) * 128 + d] = sA[r] + sB[r];
}

// ---------------- gate logits+top2 from hfull ----------------
__global__ __launch_bounds__(256) void gate_logits(
    const float* __restrict__ hfull, const float* __restrict__ b1,
    const float* __restrict__ w2, const float* __restrict__ b2,
    int* __restrict__ gidx, float* __restrict__ gw)
{
  __shared__ float hs[16][128];
  __shared__ float ls[16][8];
  const int t  = threadIdx.x;
  const int p0 = blockIdx.x * 16;

  for (int i = t; i < 2048; i += 256) {
    int p = i >> 7, d = i & 127;
    hs[p][d] = fmaxf(hfull[((size_t)(p0 + p)) * 128 + d] + b1[d], 0.f);
  }
  __syncthreads();

  if (t < 128) {
    int p = t >> 3, e = t & 7;
    float s = 0.f;
    for (int d0 = 0; d0 < 128; d0 += 32) {
      float cs = 0.f;
#pragma unroll
      for (int dd = 0; dd < 32; ++dd)
        cs = fmaf(hs[p][d0 + dd], w2[(d0 + dd) * 8 + e], cs);
      s += cs;
    }
    ls[p][e] = s + b2[e];
  }
  __syncthreads();

  if (t < 16) {
    int gp = p0 + t;
    float v[8];
#pragma unroll
    for (int e = 0; e < 8; ++e) v[e] = ls[t][e];
    int e0 = 0;
#pragma unroll
    for (int e = 1; e < 8; ++e) if (v[e] > v[e0]) e0 = e;
    int e1 = (e0 == 0) ? 1 : 0;
#pragma unroll
    for (int e = 0; e < 8; ++e) { if (e != e0 && v[e] > v[e1]) e1 = e; }
    float bexp = expf(v[e1] - v[e0]);
    float inv  = 1.f / (1.f + bexp);
    gidx[gp * 2 + 0] = e0;
    gidx[gp * 2 + 1] = e1;
    gw[gp * 2 + 0] = inv;
    gw[gp * 2 + 1] = bexp * inv;
  }
}

// ================= r10 full-K gate machinery (fallback) =================
#define GATE_DECLS                                                                  \
  const int t  = threadIdx.x;                                                       \
  const int l  = t & 63;                                                            \
  const int wv = t >> 6;                                                            \
  const int mrow  = l & 15;                                                         \
  const int kslot = l >> 4;                                                         \
  const int sp   = l & 15;                                                          \
  const int sj4  = (l >> 4) + 4 * (wv & 1);                                         \
  const int srr0 = (wv >> 1);                                                       \
  const int srr1 = 4 + (wv >> 1);

#define SLOAD(ch, R0, R1) do {                                                      \
    R0 = *(const float4*)&x[pbase + (size_t)((ch) >> 2) * 262144 +                  \
                            (size_t)(((ch) & 3) * 8 + srr0) * 512 + sj4 * 4];       \
    R1 = *(const float4*)&x[pbase + (size_t)((ch) >> 2) * 262144 +                  \
                            (size_t)(((ch) & 3) * 8 + srr1) * 512 + sj4 * 4];       \
  } while (0)

#define SPLIT4(V, HP, LP) do {                                                      \
    bf16x4 h_, lo_;                                                                 \
    h_[0] = (__bf16)V.x; lo_[0] = (__bf16)(V.x - (float)h_[0]);                     \
    h_[1] = (__bf16)V.y; lo_[1] = (__bf16)(V.y - (float)h_[1]);                     \
    h_[2] = (__bf16)V.z; lo_[2] = (__bf16)(V.z - (float)h_[2]);                     \
    h_[3] = (__bf16)V.w; lo_[3] = (__bf16)(V.w - (float)h_[3]);                     \
    *(bf16x4*)(HP) = h_; *(bf16x4*)(LP) = lo_;                                      \
  } while (0)

#define SSTORE(ch, R0, R1) do {                                                     \
    const int bf_ = (ch) & 1;                                                       \
    SPLIT4(R0, &Ah[bf_][srr0][(sj4 >> 1) * 16 + sp][(sj4 & 1) * 4],                 \
               &Al[bf_][srr0][(sj4 >> 1) * 16 + sp][(sj4 & 1) * 4]);                \
    SPLIT4(R1, &Ah[bf_][srr1][(sj4 >> 1) * 16 + sp][(sj4 & 1) * 4],                 \
               &Al[bf_][srr1][(sj4 >> 1) * 16 + sp][(sj4 & 1) * 4]);                \
  } while (0)

#define BLOAD(ch, BH, BL) do {                                                      \
    const bf16x8* wp_ = w1f + (size_t)(ch) * 4096 + wv * 64 + l;                    \
    _Pragma("unroll")                                                               \
    for (int q = 0; q < 8; ++q) { BH[q] = wp_[q * 512]; BL[q] = wp_[NFRAG + q * 512]; } \
  } while (0)

#define MFMA_PASS(ch, BH, BL) do {                                                  \
    const int bf_ = (ch) & 1;                                                       \
    _Pragma("unroll")                                                               \
    for (int ktl = 0; ktl < 8; ++ktl) {                                             \
      bf16x8 ah_ = *(const bf16x8*)&Ah[bf_][ktl][l][0];                             \
      bf16x8 al_ = *(const bf16x8*)&Al[bf_][ktl][l][0];                             \
      const int r_ = ktl & 3;                                                       \
      accA[r_] = __builtin_amdgcn_mfma_f32_16x16x32_bf16(ah_, BH[ktl], accA[r_], 0, 0, 0); \
      accB[r_] = __builtin_amdgcn_mfma_f32_16x16x32_bf16(ah_, BL[ktl], accB[r_], 0, 0, 0); \
      accB[r_] = __builtin_amdgcn_mfma_f32_16x16x32_bf16(al_, BH[ktl], accB[r_], 0, 0, 0); \
    }                                                                               \
  } while (0)

__global__ __launch_bounds__(512) void gate_mfma(
    const float* __restrict__ x, const bf16x8* __restrict__ w1f,
    const float* __restrict__ b1, const float* __restrict__ w2,
    const float* __restrict__ b2, int* __restrict__ gidx,
    float* __restrict__ gw)
{
  __shared__ __bf16 Ah[2][8][64][8];
  __shared__ __bf16 Al[2][8][64][8];
  __shared__ float hs[16][128];
  __shared__ float ls[16][8];

  GATE_DECLS
  const int p0 = blockIdx.x * 16;

  size_t pbase;
  {
    int gp = p0 + sp;
    int bb = gp >> 8, ph = (gp >> 4) & 15, pwc = gp & 15;
    pbase = ((size_t)(bb * 3) * 512 + ph * 32) * 512 + pwc * 32;
  }

  f32x4 accA[4], accB[4];
#pragma unroll
  for (int i = 0; i < 4; ++i) {
    accA[i] = (f32x4){0.f, 0.f, 0.f, 0.f};
    accB[i] = (f32x4){0.f, 0.f, 0.f, 0.f};
  }

  float4 r0, r1;
  bf16x8 bh0[8], bl0[8], bh1[8], bl1[8];

  SLOAD(0, r0, r1);
  BLOAD(0, bh0, bl0);
  SSTORE(0, r0, r1);
  __syncthreads();

#pragma unroll
  for (int cc = 0; cc < 12; cc += 2) {
    if (cc + 1 < 12) { SLOAD(cc + 1, r0, r1); BLOAD(cc + 1, bh1, bl1); }
    MFMA_PASS(cc, bh0, bl0);
    if (cc + 1 < 12) SSTORE(cc + 1, r0, r1);
    __syncthreads();
    if (cc + 2 < 12) { SLOAD(cc + 2, r0, r1); BLOAD(cc + 2, bh0, bl0); }
    MFMA_PASS(cc + 1, bh1, bl1);
    if (cc + 2 < 12) SSTORE(cc + 2, r0, r1);
    __syncthreads();
  }

  {
    f32x4 sA = (accA[0] + accA[1]) + (accA[2] + accA[3]);
    f32x4 sB = (accB[0] + accB[1]) + (accB[2] + accB[3]);
    const int d = wv * 16 + mrow;
    const float bb1 = b1[d];
#pragma unroll
    for (int r = 0; r < 4; ++r) {
      int m = kslot * 4 + r;
      hs[m][d] = fmaxf(sA[r] + sB[r] + bb1, 0.f);
    }
  }
  __syncthreads();

  if (t < 128) {
    int p = t >> 3, e = t & 7;
    float s = 0.f;
    for (int d0 = 0; d0 < 128; d0 += 32) {
      float cs = 0.f;
#pragma unroll
      for (int dd = 0; dd < 32; ++dd)
        cs = fmaf(hs[p][d0 + dd], w2[(d0 + dd) * 8 + e], cs);
      s += cs;
    }
    ls[p][e] = s + b2[e];
  }
  __syncthreads();

  if (t < 16) {
    int gp = p0 + t;
    float v[8];
#pragma unroll
    for (int e = 0; e < 8; ++e) v[e] = ls[t][e];
    int e0 = 0;
#pragma unroll
    for (int e = 1; e < 8; ++e) if (v[e] > v[e0]) e0 = e;
    int e1 = (e0 == 0) ? 1 : 0;
#pragma unroll
    for (int e = 0; e < 8; ++e) { if (e != e0 && v[e] > v[e1]) e1 = e; }
    float bexp = expf(v[e1] - v[e0]);
    float inv  = 1.f / (1.f + bexp);
    gidx[gp * 2 + 0] = e0;
    gidx[gp * 2 + 1] = e1;
    gw[gp * 2 + 0] = inv;
    gw[gp * 2 + 1] = bexp * inv;
  }
}

// ---------------- fallback gate (r8, proven) ----------------
__global__ __launch_bounds__(512, 4) void gate_kernel(
    const float* __restrict__ x, const float* __restrict__ w1,
    const float* __restrict__ b1, const float* __restrict__ w2,
    const float* __restrict__ b2, int* __restrict__ gidx,
    float* __restrict__ gw)
{
  __shared__ float As[8][1024];
  __shared__ float hs[8][128];
  __shared__ float ls[8][8];

  const int t   = threadIdx.x;
  const int p0  = blockIdx.x * 8;
  const int d   = t & 127;
  const int grp = t >> 7;
  const int pa  = grp * 2, pb = grp * 2 + 1;

  float acc0 = 0.f, acc1 = 0.f;

  for (int c = 0; c < 3; ++c) {
#pragma unroll
    for (int it = 0; it < 4; ++it) {
      int i = t + it * 512;
      int p = i >> 8, rem = i & 255, r = rem >> 3, j4 = (rem & 7) * 4;
      int gp = p0 + p;
      int bb = gp >> 8, ph = (gp >> 4) & 15, pwc = gp & 15;
      *(float4*)&As[p][r * 32 + j4] =
          *(const float4*)&x[((size_t)(bb * 3 + c) * 512 + ph * 32 + r) * 512 + pwc * 32 + j4];
    }
    __syncthreads();

    const float* wdp = w1 + (size_t)c * 131072 + d;
    for (int ch = 0; ch < 32; ++ch) {
      float bv[32];
#pragma unroll
      for (int j = 0; j < 32; ++j) bv[j] = wdp[(ch * 32 + j) * 128];
      const int kl = ch * 32;
      float ca = 0.f, cb = 0.f;
#pragma unroll
      for (int q = 0; q < 8; ++q) {
        float4 a0 = *(const float4*)&As[pa][kl + q * 4];
        float4 a1 = *(const float4*)&As[pb][kl + q * 4];
        ca = fmaf(a0.x, bv[q * 4 + 0], ca); ca = fmaf(a0.y, bv[q * 4 + 1], ca);
        ca = fmaf(a0.z, bv[q * 4 + 2], ca); ca = fmaf(a0.w, bv[q * 4 + 3], ca);
        cb = fmaf(a1.x, bv[q * 4 + 0], cb); cb = fmaf(a1.y, bv[q * 4 + 1], cb);
        cb = fmaf(a1.z, bv[q * 4 + 2], cb); cb = fmaf(a1.w, bv[q * 4 + 3], cb);
      }
      acc0 += ca; acc1 += cb;
    }
    __syncthreads();
  }

  hs[pa][d] = fmaxf(acc0 + b1[d], 0.f);
  hs[pb][d] = fmaxf(acc1 + b1[d], 0.f);
  __syncthreads();

  if (t < 64) {
    int p = t >> 3, e = t & 7;
    float s = 0.f;
    for (int d0 = 0; d0 < 128; d0 += 32) {
      float cs = 0.f;
#pragma unroll
      for (int dd = 0; dd < 32; ++dd)
        cs = fmaf(hs[p][d0 + dd], w2[(d0 + dd) * 8 + e], cs);
      s += cs;
    }
    ls[p][e] = s + b2[e];
  }
  __syncthreads();

  if (t < 8) {
    int gp = p0 + t;
    float v[8];
#pragma unroll
    for (int e = 0; e < 8; ++e) v[e] = ls[t][e];
    int e0 = 0;
#pragma unroll
    for (int e = 1; e < 8; ++e) if (v[e] > v[e0]) e0 = e;
    int e1 = (e0 == 0) ? 1 : 0;
#pragma unroll
    for (int e = 0; e < 8; ++e) { if (e != e0 && v[e] > v[e1]) e1 = e; }
    float bexp = expf(v[e1] - v[e0]);
    float inv  = 1.f / (1.f + bexp);
    gidx[gp * 2 + 0] = e0;
    gidx[gp * 2 + 1] = e1;
    gw[gp * 2 + 0] = inv;
    gw[gp * 2 + 1] = bexp * inv;
  }
}

// ---------------- expert kernels (byte-identical to r10/r11) ----------------
#define EXPERT_COMMON_PRE                                                          \
  __shared__ float  ps[3][32][36];                                                 \
  __shared__ float  y1s[3][256];                                                   \
  __shared__ __bf16 y3b[64][140];                                                  \
  __shared__ float  posum[4][128];                                                 \
  __shared__ float  outbuf[128];                                                   \
  const int t  = threadIdx.x;                                                      \
  const int gp = blockIdx.x;                                                       \
  const int b = gp >> 8, ph = (gp >> 4) & 15, pw = gp & 15;                        \
  const int l = t & 63, wv = t >> 6;                                               \
  _Pragma("unroll")                                                                \
  for (int it = 0; it < 3; ++it) {                                                 \
    int f4i = t + 256 * it;                                                        \
    int c = f4i >> 8, r = (f4i >> 3) & 31, j4 = f4i & 7;                           \
    *(float4*)&ps[c][r][j4 * 4] =                                                  \
        *(const float4*)&x[((size_t)(b * 3 + c) * 512 + ph * 32 + r) * 512 +       \
                           pw * 32 + j4 * 4];                                      \
  }                                                                                \
  if (t < 128) outbuf[t] = 0.f;                                                    \
  const int dd   = t & 127;                                                        \
  const int half = t >> 7;                                                         \
  __syncthreads();

#define EXPERT_PHASES_1_2                                                          \
    for (int oi = t; oi < 768; oi += 256) {                                        \
      int c = oi >> 8, p = (oi >> 4) & 15, q = oi & 15;                            \
      float a = dw1_b[e * 3 + c];                                                  \
      const float* wp_ = &dw1_w[(e * 3 + c) * 9];                                  \
      _Pragma("unroll")                                                            \
      for (int di = 0; di < 3; ++di) {                                             \
        int ii = 2 * p + di - 1;                                                   \
        if (ii < 0) continue;                                                      \
        _Pragma("unroll")                                                          \
        for (int dj = 0; dj < 3; ++dj) {                                           \
          int jj = 2 * q + dj - 1;                                                 \
          if (jj < 0) continue;                                                    \
          a = fmaf(wp_[di * 3 + dj], ps[c][ii][jj], a);                            \
        }                                                                          \
      }                                                                            \
      y1s[c][p * 16 + q] = fmaxf(a, 0.f);                                          \
    }                                                                              \
    __syncthreads();                                                               \
    {                                                                              \
      const float pwa = pw1_w[(e * 128 + dd) * 3 + 0];                             \
      const float pwb = pw1_w[(e * 128 + dd) * 3 + 1];                             \
      const float pwc = pw1_w[(e * 128 + dd) * 3 + 2];                             \
      const float pb  = pw1_b[e * 128 + dd];                                       \
      float dwv[9];                                                                \
      _Pragma("unroll")                                                            \
      for (int i = 0; i < 9; ++i) dwv[i] = dw2_w[(e * 128 + dd) * 9 + i];          \
      const float db = dw2_b[e * 128 + dd];                                        \
      for (int u = half * 4; u < half * 4 + 4; ++u) {                              \
        float vacc[8];                                                             \
        _Pragma("unroll")                                                          \
        for (int v = 0; v < 8; ++v) vacc[v] = db;                                  \
        _Pragma("unroll")                                                          \
        for (int di = 0; di < 3; ++di) {                                           \
          int ii = 2 * u + di - 1;                                                 \
          if (ii < 0) continue;                                                    \
          float y2row[16];                                                         \
          _Pragma("unroll")                                                        \
          for (int q4 = 0; q4 < 4; ++q4) {                                         \
            float4 a  = *(const float4*)&y1s[0][ii * 16 + q4 * 4];                 \
            float4 bq = *(const float4*)&y1s[1][ii * 16 + q4 * 4];                 \
            float4 cq = *(const float4*)&y1s[2][ii * 16 + q4 * 4];                 \
            y2row[q4 * 4 + 0] = fmaxf(fmaf(pwa, a.x, fmaf(pwb, bq.x, fmaf(pwc, cq.x, pb))), 0.f); \
            y2row[q4 * 4 + 1] = fmaxf(fmaf(pwa, a.y, fmaf(pwb, bq.y, fmaf(pwc, cq.y, pb))), 0.f); \
            y2row[q4 * 4 + 2] = fmaxf(fmaf(pwa, a.z, fmaf(pwb, bq.z, fmaf(pwc, cq.z, pb))), 0.f); \
            y2row[q4 * 4 + 3] = fmaxf(fmaf(pwa, a.w, fmaf(pwb, bq.w, fmaf(pwc, cq.w, pb))), 0.f); \
          }                                                                        \
          _Pragma("unroll")                                                        \
          for (int v = 0; v < 8; ++v) {                                            \
            _Pragma("unroll")                                                      \
            for (int dj = 0; dj < 3; ++dj) {                                       \
              int jj = 2 * v + dj - 1;                                             \
              if (jj < 0) continue;                                                \
              vacc[v] = fmaf(dwv[di * 3 + dj], y2row[jj], vacc[v]);                \
            }                                                                      \
          }                                                                        \
        }                                                                          \
        _Pragma("unroll")                                                          \
        for (int v = 0; v < 8; ++v)                                                \
          y3b[u * 8 + v][dd] = (__bf16)fmaxf(vacc[v], 0.f);                        \
      }                                                                            \
    }

#define EXPERT_EPILOG                                                              \
    _Pragma("unroll")                                                              \
    for (int nt = 0; nt < 8; ++nt) {                                               \
      float bias = pw2_b[e * 128 + nt * 16 + (l & 15)];                            \
      float s = fmaxf(acc[nt][0] + bias, 0.f) + fmaxf(acc[nt][1] + bias, 0.f)      \
              + fmaxf(acc[nt][2] + bias, 0.f) + fmaxf(acc[nt][3] + bias, 0.f);     \
      s += __shfl_xor(s, 16);                                                      \
      s += __shfl_xor(s, 32);                                                      \
      if (l < 16) posum[wv][nt * 16 + l] = s;                                      \
    }

__global__ __launch_bounds__(256, 4) void expert_packed(
    const float* __restrict__ x,
    const float* __restrict__ dw1_w, const float* __restrict__ dw1_b,
    const float* __restrict__ pw1_w, const float* __restrict__ pw1_b,
    const float* __restrict__ dw2_w, const float* __restrict__ dw2_b,
    const bf16x8* __restrict__ wpk, const float* __restrict__ pw2_b,
    const int* __restrict__ gidx, const float* __restrict__ gw,
    float* __restrict__ out)
{
  EXPERT_COMMON_PRE
  for (int k = 0; k < 2; ++k) {
    const int   e  = gidx[gp * 2 + k];
    const float wk = gw[gp * 2 + k];
    EXPERT_PHASES_1_2
    __syncthreads();
    {
      f32x4 acc[8];
#pragma unroll
      for (int nt = 0; nt < 8; ++nt) acc[nt] = (f32x4){0.f, 0.f, 0.f, 0.f};
      const int row  = wv * 16 + (l & 15);
      const int kofs = (l >> 4) * 8;
      bf16x8 afrag[4];
#pragma unroll
      for (int kt = 0; kt < 4; ++kt)
        afrag[kt] = *(const bf16x8*)&y3b[row][kt * 32 + kofs];
      const bf16x8* wb = wpk + (size_t)e * 2048 + l;
#pragma unroll
      for (int kt = 0; kt < 4; ++kt) {
        bf16x8 bf[8];
#pragma unroll
        for (int nt = 0; nt < 8; ++nt) bf[nt] = wb[(kt * 8 + nt) * 64];
#pragma unroll
        for (int nt = 0; nt < 8; ++nt)
          acc[nt] = __builtin_amdgcn_mfma_f32_16x16x32_bf16(afrag[kt], bf[nt], acc[nt], 0, 0, 0);
      }
      EXPERT_EPILOG
    }
    __syncthreads();
    if (t < 128)
      outbuf[t] += wk * 0.015625f *
                   (posum[0][t] + posum[1][t] + posum[2][t] + posum[3][t]);
    __syncthreads();
  }
  if (t < 128)
    out[((size_t)(b * 128 + t) * 16 + ph) * 16 + pw] = outbuf[t];
}

__global__ __launch_bounds__(256) void expert_fb(
    const float* __restrict__ x,
    const float* __restrict__ dw1_w, const float* __restrict__ dw1_b,
    const float* __restrict__ pw1_w, const float* __restrict__ pw1_b,
    const float* __restrict__ dw2_w, const float* __restrict__ dw2_b,
    const float* __restrict__ pw2_w, const float* __restrict__ pw2_b,
    const int* __restrict__ gidx, const float* __restrict__ gw,
    float* __restrict__ out)
{
  __shared__ __bf16 wlds[128][136];
  EXPERT_COMMON_PRE
  for (int k = 0; k < 2; ++k) {
    const int   e  = gidx[gp * 2 + k];
    const float wk = gw[gp * 2 + k];
    EXPERT_PHASES_1_2
    for (int i4 = t; i4 < 4096; i4 += 256) {
      int n = i4 >> 5, kq = i4 & 31;
      float4 w4 = *(const float4*)&pw2_w[((size_t)(e * 128 + n)) * 128 + kq * 4];
      bf16x4 pk = { (__bf16)w4.x, (__bf16)w4.y, (__bf16)w4.z, (__bf16)w4.w };
      *(bf16x4*)&wlds[n][kq * 4] = pk;
    }
    __syncthreads();
    {
      f32x4 acc[8];
#pragma unroll
      for (int nt = 0; nt < 8; ++nt) acc[nt] = (f32x4){0.f, 0.f, 0.f, 0.f};
      const int row  = wv * 16 + (l & 15);
      const int kofs = (l >> 4) * 8;
      bf16x8 afrag[4];
#pragma unroll
      for (int kt = 0; kt < 4; ++kt)
        afrag[kt] = *(const bf16x8*)&y3b[row][kt * 32 + kofs];
#pragma unroll
      for (int kt = 0; kt < 4; ++kt) {
#pragma unroll
        for (int nt = 0; nt < 8; ++nt) {
          bf16x8 bfrag = *(const bf16x8*)&wlds[nt * 16 + (l & 15)][kt * 32 + kofs];
          acc[nt] = __builtin_amdgcn_mfma_f32_16x16x32_bf16(afrag[kt], bfrag, acc[nt], 0, 0, 0);
        }
      }
      EXPERT_EPILOG
    }
    __syncthreads();
    if (t < 128)
      outbuf[t] += wk * 0.015625f *
                   (posum[0][t] + posum[1][t] + posum[2][t] + posum[3][t]);
    __syncthreads();
  }
  if (t < 128)
    out[((size_t)(b * 128 + t) * 16 + ph) * 16 + pw] = outbuf[t];
}

extern "C" void kernel_launch(void* const* d_in, const int* in_sizes, int n_in,
                              void* d_out, int out_size, void* d_ws, size_t ws_size,
                              hipStream_t stream) {
  const float* x       = (const float*)d_in[0];
  const float* gate_w1 = (const float*)d_in[1];
  const float* gate_b1 = (const float*)d_in[2];
  const float* gate_w2 = (const float*)d_in[3];
  const float* gate_b2 = (const float*)d_in[4];
  const float* dw1_w   = (const float*)d_in[5];
  const float* dw1_b   = (const float*)d_in[6];
  const float* pw1_w   = (const float*)d_in[7];
  const float* pw1_b   = (const float*)d_in[8];
  const float* dw2_w   = (const float*)d_in[9];
  const float* dw2_b   = (const float*)d_in[10];
  const float* pw2_w   = (const float*)d_in[11];
  const float* pw2_b   = (const float*)d_in[12];
  float* out = (float*)d_out;

  const size_t off_wpk   = (size_t)NPATCH * 4 * sizeof(int);         // 64 KB
  const size_t off_w1f   = off_wpk + 256 * 1024;                     // 320 KB
  const size_t off_afr   = off_w1f + (size_t)NFRAG * 2 * 16;         // ~1.86 MB
  const size_t off_hfull = off_afr + (size_t)NA * 2 * 16;            // ~52.2 MB
  const size_t ws_pack   = off_w1f;
  const size_t ws_full   = off_afr;
  const size_t ws_wavegt = off_hfull + (size_t)NPATCH * 128 * sizeof(float);  // ~54.3 MB

  int*    gidx  = (int*)d_ws;
  float*  gw    = (float*)((char*)d_ws + (size_t)NPATCH * 2 * sizeof(int));
  bf16x8* wpk   = (bf16x8*)((char*)d_ws + off_wpk);
  bf16x8* w1f   = (bf16x8*)((char*)d_ws + off_w1f);
  bf16x8* afr   = (bf16x8*)((char*)d_ws + off_afr);
  float*  hfull = (float*)((char*)d_ws + off_hfull);

  const bool packed = ws_size >= ws_pack;
  const bool mfgate = ws_size >= ws_full;
  const bool wavegt = ws_size >= ws_wavegt;

  if (wavegt) {
    prep_w1<<<192, 256, 0, stream>>>(gate_w1, w1f);
    prep_x<<<6144, 256, 0, stream>>>(x, afr);
    gate_wave<<<2048, 64, 0, stream>>>(afr, w1f, hfull);
    gate_logits<<<NPATCH / 16, 256, 0, stream>>>(hfull, gate_b1, gate_w2, gate_b2, gidx, gw);
  } else if (mfgate) {
    prep_w1<<<192, 256, 0, stream>>>(gate_w1, w1f);
    gate_mfma<<<NPATCH / 16, 512, 0, stream>>>(x, w1f, gate_b1, gate_w2, gate_b2, gidx, gw);
  } else {
    gate_kernel<<<NPATCH / 8, 512, 0, stream>>>(x, gate_w1, gate_b1, gate_w2, gate_b2, gidx, gw);
  }
  if (packed) {
    prep_kernel<<<64, 256, 0, stream>>>(pw2_w, wpk);
    expert_packed<<<NPATCH, 256, 0, stream>>>(x, dw1_w, dw1_b, pw1_w, pw1_b,
                                              dw2_w, dw2_b, wpk, pw2_b, gidx, gw, out);
  } else {
    expert_fb<<<NPATCH, 256, 0, stream>>>(x, dw1_w, dw1_b, pw1_w, pw1_b,
                                          dw2_w, dw2_b, pw2_w, pw2_b, gidx, gw, out);
  }
}